// Round 9
// baseline (73.032 us; speedup 1.0000x reference)
//
#include <hip/hip_runtime.h>
#include <cstdint>
#include <cstddef>

// Fused prefix-LM self-attention, B=8192, S=64, D=32, H=4, DH=8.
// Block = 128 thr = 2 waves = 1 batch. R9: waves split by SEQUENCE, not
// head: wave w owns i-tiles {w, 3-w} (diagonal pairing balances the
// causal-mask skip) for ALL 4 heads -> final out-projection needs no
// cross-wave exchange (direct stores), x loaded once per block.
// K^T/V^T staged cooperatively in shared LDS (one __syncthreads).
// bf16 MFMA 16x16x32 end-to-end; Q^T in registers; P through per-wave
// LDS slice (DS pipe in-order per wave). Streaming softmax, no max
// subtraction (|score|<~2). Wave-uniform skip of fully-masked tiles
// (mask monotone in j: skip iff 16*jt > max(i_max, aab-1)).
#define NB 8192

typedef __attribute__((ext_vector_type(8))) short short8;
typedef __attribute__((ext_vector_type(4))) float f32x4;

union S8U { short8 s; unsigned u[4]; uint4 v; };

static __device__ __forceinline__ unsigned pk2(float a, float b) {
    unsigned short ua = __builtin_bit_cast(unsigned short, (__bf16)a);
    unsigned short ub = __builtin_bit_cast(unsigned short, (__bf16)b);
    return (unsigned)ua | ((unsigned)ub << 16);
}

#define MFMA __builtin_amdgcn_mfma_f32_16x16x32_bf16
#define BPERM __builtin_amdgcn_ds_bpermute
// compiler-only fence: pins in-wave LDS write->read program order
#define LDSFENCE() asm volatile("" ::: "memory")

__global__ __launch_bounds__(128, 4) void fused_attn_mfma(
    const float* __restrict__ x,
    const int*   __restrict__ aatt,
    const float* __restrict__ Wq, const float* __restrict__ bq,
    const float* __restrict__ Wk, const float* __restrict__ bk,
    const float* __restrict__ Wv, const float* __restrict__ bv,
    const float* __restrict__ Wp, const float* __restrict__ bp,
    float* __restrict__ out)
{
    __shared__ __align__(16) short klds[64][40];   // K[seq][dim], 80B rows (5120B)
    __shared__ __align__(16) short vbt[32][72];    // V^T[dim][seq], 144B rows (4608B)
    __shared__ __align__(16) short psl[2][16][40]; // per-wave P slice (2560B)

    const int tid  = threadIdx.x;
    const int w    = tid >> 6;
    const int lane = tid & 63;
    const int q4   = lane >> 4;
    const int l15  = lane & 15;
    const int b    = blockIdx.x;

    const int aab = aatt[b];
    const unsigned bmask = (q4 == 0) ? 0xFFFFFFFFu : 0u;

    // this wave's i-tiles (and staging seq-tiles): {0,3} or {1,2}
    const int tg0 = w ? 1 : 0;
    const int tg1 = w ? 2 : 3;

    // per-lane mask compare: allowed(j) == jb*32+jt*16+r <= cmpv[u]
    int cmpv[2];
    cmpv[0] = max(tg0 * 16 + l15, aab - 1) - q4 * 4;
    cmpv[1] = max(tg1 * 16 + l15, aab - 1) - q4 * 4;
    // wave-uniform tile-skip compare
    const int umax0 = max(tg0 * 16 + 15, aab - 1);
    const int umax1 = max(tg1 * 16 + 15, aab - 1);

    // ---- X fragments for this wave's two seq-tiles ----
    short8 xa[2];
    const float* xb = x + (size_t)b * 64 * 32;
    {
        const int tg[2] = { tg0, tg1 };
#pragma unroll
        for (int u = 0; u < 2; ++u) {
            const float* p = xb + (tg[u] * 16 + l15) * 32 + q4 * 8;
            float4 u0 = *(const float4*)p;
            float4 u1 = *(const float4*)(p + 4);
            S8U t;
            t.u[0] = pk2(u0.x, u0.y); t.u[1] = pk2(u0.z, u0.w);
            t.u[2] = pk2(u1.x, u1.y); t.u[3] = pk2(u1.z, u1.w);
            xa[u] = t.s;
        }
    }

    auto wrow = [&](const float* W, int row) -> short8 {
        const float* p = W + row * 32 + q4 * 8;
        float4 u0 = *(const float4*)p;
        float4 u1 = *(const float4*)(p + 4);
        S8U t;
        t.u[0] = pk2(u0.x, u0.y); t.u[1] = pk2(u0.z, u0.w);
        t.u[2] = pk2(u1.x, u1.y); t.u[3] = pk2(u1.z, u1.w);
        return t.s;
    };

    const float escale = 0.35355339059327373f * 1.4426950408889634f; // 1/sqrt(8)*log2(e)

    // ---- Q^T (all 32 dims, this wave's i-tiles) -> registers ----
    unsigned qpk01[2][2], qpk23[2][2];   // [mt][u]
#pragma unroll
    for (int mt = 0; mt < 2; ++mt) {
        short8 wa = wrow(Wq, mt * 16 + l15);
        float4 b4 = *(const float4*)(bq + mt * 16 + q4 * 4);
        const float bx = b4.x * escale, by = b4.y * escale,
                    bz = b4.z * escale, bw = b4.w * escale;
#pragma unroll
        for (int u = 0; u < 2; ++u) {
            f32x4 acc = {0.f, 0.f, 0.f, 0.f};
            acc = MFMA(wa, xa[u], acc, 0, 0, 0);
            qpk01[mt][u] = pk2(fmaf(acc[0], escale, bx), fmaf(acc[1], escale, by));
            qpk23[mt][u] = pk2(fmaf(acc[2], escale, bz), fmaf(acc[3], escale, bw));
        }
    }
    // ---- K^T (all 32 dims, this wave's seq-tiles) -> klds ----
#pragma unroll
    for (int mt = 0; mt < 2; ++mt) {
        short8 wa = wrow(Wk, mt * 16 + l15);
        float4 b4 = *(const float4*)(bk + mt * 16 + q4 * 4);
        const int tg[2] = { tg0, tg1 };
#pragma unroll
        for (int u = 0; u < 2; ++u) {
            f32x4 acc = {0.f, 0.f, 0.f, 0.f};
            acc = MFMA(wa, xa[u], acc, 0, 0, 0);
            uint2 w2;
            w2.x = pk2(acc[0] + b4.x, acc[1] + b4.y);
            w2.y = pk2(acc[2] + b4.z, acc[3] + b4.w);
            *(uint2*)&klds[tg[u] * 16 + l15][mt * 16 + q4 * 4] = w2;
        }
    }
    // ---- V (this wave's seq-tiles, all 32 dims) -> vbt (V^T) ----
#pragma unroll
    for (int nt = 0; nt < 2; ++nt) {
        short8 wv = wrow(Wv, nt * 16 + l15);
        const float bvv = bv[nt * 16 + l15];
        const int tg[2] = { tg0, tg1 };
#pragma unroll
        for (int u = 0; u < 2; ++u) {
            f32x4 acc = {0.f, 0.f, 0.f, 0.f};
            acc = MFMA(xa[u], wv, acc, 0, 0, 0);
            uint2 w2;
            w2.x = pk2(acc[0] + bvv, acc[1] + bvv);
            w2.y = pk2(acc[2] + bvv, acc[3] + bvv);
            *(uint2*)&vbt[nt * 16 + l15][tg[u] * 16 + q4 * 4] = w2;
        }
    }
    __syncthreads();   // K/V staging is cross-wave shared

    // ---- head loop: all 4 heads, this wave's 2 i-tiles ----
    unsigned opk01s[4][2], opk23s[4][2];

#pragma unroll
    for (int h = 0; h < 4; ++h) {
        const int mth = h >> 1;
        const int p   = h & 1;
        const int idxA = (32 * p + l15) * 4;
        const int idxB = idxA + 64;

        // Q B-frags for both i-tiles (zero k>=8 via bmask)
        short8 sqb[2];
#pragma unroll
        for (int u = 0; u < 2; ++u) {
            S8U t;
            t.u[0] = (unsigned)BPERM(idxA, (int)qpk01[mth][u]) & bmask;
            t.u[1] = (unsigned)BPERM(idxA, (int)qpk23[mth][u]) & bmask;
            t.u[2] = (unsigned)BPERM(idxB, (int)qpk01[mth][u]) & bmask;
            t.u[3] = (unsigned)BPERM(idxB, (int)qpk23[mth][u]) & bmask;
            sqb[u] = t.s;
        }

#pragma unroll
        for (int u = 0; u < 2; ++u) {
            const int umax = u ? umax1 : umax0;
            const int cmp  = cmpv[u];
            float csum = 0.0f;
            f32x4 oacc = {0.f, 0.f, 0.f, 0.f};

#pragma unroll
            for (int jb = 0; jb < 2; ++jb) {
                if (32 * jb > umax) continue;          // fully-masked PV unit
                const bool skip1 = (32 * jb + 16 > umax);

                // jt = 0 (never masked when this unit runs)
                {
                    S8U t; t.v = *(const uint4*)&klds[jb * 32 + l15][8 * h];
                    f32x4 sacc = {0.f, 0.f, 0.f, 0.f};
                    sacc = MFMA(t.s, sqb[u], sacc, 0, 0, 0);
                    float e[4];
#pragma unroll
                    for (int r = 0; r < 4; ++r) {
                        float ee = __builtin_amdgcn_exp2f(sacc[r]);
                        e[r] = (jb * 32 + r <= cmp) ? ee : 0.0f;
                    }
                    csum += (e[0] + e[1]) + (e[2] + e[3]);
                    uint2 pw; pw.x = pk2(e[0], e[1]); pw.y = pk2(e[2], e[3]);
                    *(uint2*)&psl[w][l15][q4 * 4] = pw;
                }
                // jt = 1: compute or zero-fill
                if (!skip1) {
                    S8U t; t.v = *(const uint4*)&klds[jb * 32 + 16 + l15][8 * h];
                    f32x4 sacc = {0.f, 0.f, 0.f, 0.f};
                    sacc = MFMA(t.s, sqb[u], sacc, 0, 0, 0);
                    float e[4];
#pragma unroll
                    for (int r = 0; r < 4; ++r) {
                        float ee = __builtin_amdgcn_exp2f(sacc[r]);
                        e[r] = (jb * 32 + 16 + r <= cmp) ? ee : 0.0f;
                    }
                    csum += (e[0] + e[1]) + (e[2] + e[3]);
                    uint2 pw; pw.x = pk2(e[0], e[1]); pw.y = pk2(e[2], e[3]);
                    *(uint2*)&psl[w][l15][16 + q4 * 4] = pw;
                } else {
                    uint2 pw; pw.x = 0u; pw.y = 0u;
                    *(uint2*)&psl[w][l15][16 + q4 * 4] = pw;
                }

                LDSFENCE();
                S8U pb; pb.v = *(const uint4*)&psl[w][l15][q4 * 8];
                S8U av; av.v = *(const uint4*)&vbt[8 * h + (l15 & 7)][jb * 32 + q4 * 8];
                oacc = MFMA(av.s, pb.s, oacc, 0, 0, 0);
                LDSFENCE();
            }

            // column sum + normalize -> packed O-frags
            float a = csum;
            a += __shfl_xor(a, 16, 64);
            a += __shfl_xor(a, 32, 64);
            const float inv = __builtin_amdgcn_rcpf(a);
            opk01s[h][u] = pk2(oacc[0] * inv, oacc[1] * inv);
            opk23s[h][u] = pk2(oacc[2] * inv, oacc[3] * inv);
        }
    }

    // ---- tail: Y = sum_h O_h @ Wp_h^T for this wave's rows ----
    f32x4 yacc[2][2];
#pragma unroll
    for (int u = 0; u < 2; ++u)
#pragma unroll
        for (int nt = 0; nt < 2; ++nt) yacc[u][nt] = (f32x4){0.f, 0.f, 0.f, 0.f};

    const int idx0 = l15 * 4;
    const int idx1 = idx0 + 64;
#pragma unroll
    for (int h = 0; h < 4; ++h) {
        short8 wpb[2];
#pragma unroll
        for (int nt = 0; nt < 2; ++nt) {
            const float* p = Wp + (nt * 16 + l15) * 32 + 8 * h;
            float4 u0 = *(const float4*)p;
            float4 u1 = *(const float4*)(p + 4);
            S8U t;
            t.u[0] = pk2(u0.x, u0.y) & bmask;
            t.u[1] = pk2(u0.z, u0.w) & bmask;
            t.u[2] = pk2(u1.x, u1.y) & bmask;
            t.u[3] = pk2(u1.z, u1.w) & bmask;
            wpb[nt] = t.s;
        }
#pragma unroll
        for (int u = 0; u < 2; ++u) {
            S8U t;
            t.u[0] = (unsigned)BPERM(idx0, (int)opk01s[h][u]);
            t.u[1] = (unsigned)BPERM(idx0, (int)opk23s[h][u]);
            t.u[2] = (unsigned)BPERM(idx1, (int)opk01s[h][u]);
            t.u[3] = (unsigned)BPERM(idx1, (int)opk23s[h][u]);
#pragma unroll
            for (int nt = 0; nt < 2; ++nt)
                yacc[u][nt] = MFMA(t.s, wpb[nt], yacc[u][nt], 0, 0, 0);
        }
    }

    // ---- direct stores (this wave's 32 rows, all 32 dims) ----
    const float bpv[2] = { bp[l15], bp[16 + l15] };
    float* ob = out + (size_t)b * 64 * 32;
    const int tg[2] = { tg0, tg1 };
#pragma unroll
    for (int u = 0; u < 2; ++u)
#pragma unroll
        for (int nt = 0; nt < 2; ++nt)
#pragma unroll
            for (int r = 0; r < 4; ++r)
                ob[(tg[u] * 16 + q4 * 4 + r) * 32 + nt * 16 + l15] =
                    yacc[u][nt][r] + bpv[nt];
}

extern "C" void kernel_launch(void* const* d_in, const int* in_sizes, int n_in,
                              void* d_out, int out_size, void* d_ws, size_t ws_size,
                              hipStream_t stream) {
    const float* x  = (const float*)d_in[0];
    const int*   aa = (const int*)d_in[1];
    const float* Wq = (const float*)d_in[2];
    const float* bq = (const float*)d_in[3];
    const float* Wk = (const float*)d_in[4];
    const float* bk = (const float*)d_in[5];
    const float* Wv = (const float*)d_in[6];
    const float* bv = (const float*)d_in[7];
    const float* Wp = (const float*)d_in[8];
    const float* bp = (const float*)d_in[9];
    float* out = (float*)d_out;

    dim3 grid(NB), block(128);
    hipLaunchKernelGGL(fused_attn_mfma, grid, block, 0, stream,
                       x, aa, Wq, bq, Wk, bk, Wv, bv, Wp, bp, out);
}

// Round 10
// 50.688 us; speedup vs baseline: 1.4408x; 1.4408x over previous
//
#include <hip/hip_runtime.h>
#include <cstdint>
#include <cstddef>

// Fused prefix-LM self-attention, B=8192, S=64, D=32, H=4, DH=8.
// Block = 128 thr = 2 waves = 1 batch; wave w owns heads {2w,2w+1}
// (R8 structure, proven; R9's mask-skip machinery removed -- it saved
// no net VALU and broke the flat schedule).
// R10 changes vs R8:
//  1) colsum(P) via MFMA ones-row: vbt row 32 = 1.0; PV C rows >=8
//     (previously wasted) deliver column sums -> all csum VALU + shfl
//     reduction deleted; inv = rcp(bpermute from lane 32+l15).
//  2) tail out-projection on CONCATENATED heads: packed O written once
//     to reclaimed klds (predicated b64), 1 sync, then 4 full-K=32
//     MFMAs (vs 16 quarter-used) and direct stores. Wp masks dropped.
#define NB 8192

typedef __attribute__((ext_vector_type(8))) short short8;
typedef __attribute__((ext_vector_type(4))) float f32x4;

union S8U { short8 s; unsigned u[4]; uint4 v; };
union FI { float f; int i; unsigned u; };

static __device__ __forceinline__ unsigned pk2(float a, float b) {
    unsigned short ua = __builtin_bit_cast(unsigned short, (__bf16)a);
    unsigned short ub = __builtin_bit_cast(unsigned short, (__bf16)b);
    return (unsigned)ua | ((unsigned)ub << 16);
}

#define MFMA __builtin_amdgcn_mfma_f32_16x16x32_bf16
#define BPERM __builtin_amdgcn_ds_bpermute
// compiler-only fence: pins in-wave LDS write->read program order
#define LDSFENCE() asm volatile("" ::: "memory")

__global__ __launch_bounds__(128, 4) void fused_attn_mfma(
    const float* __restrict__ x,
    const int*   __restrict__ aatt,
    const float* __restrict__ Wq, const float* __restrict__ bq,
    const float* __restrict__ Wk, const float* __restrict__ bk,
    const float* __restrict__ Wv, const float* __restrict__ bv,
    const float* __restrict__ Wp, const float* __restrict__ bp,
    float* __restrict__ out)
{
    __shared__ __align__(16) short klds[64][40];   // K[seq][dim]; tail: O[i][dim]
    __shared__ __align__(16) short vbt[33][72];    // V^T[dim][seq] + ones row 32
    __shared__ __align__(16) short psl[2][16][40]; // per-wave P slice

    const int tid  = threadIdx.x;
    const int w    = tid >> 6;          // wave: heads {2w, 2w+1}, dims 16w..16w+15
    const int lane = tid & 63;
    const int q4   = lane >> 4;
    const int l15  = lane & 15;
    const int b    = blockIdx.x;

    const int aab = aatt[b];
    const unsigned bmask = (q4 == 0) ? 0xFFFFFFFFu : 0u;

    // allowed(j) == j <= max(i, aab-1); j = (compile-time C) + q4*4
    int cmpv[4];
#pragma unroll
    for (int it = 0; it < 4; ++it) cmpv[it] = max(l15 + 16*it, aab - 1) - q4*4;

    // ---- X fragments: row = tile*16+l15, k = q4*8+e ----
    short8 xa[4];
    const float* xb = x + (size_t)b * 64 * 32;
#pragma unroll
    for (int nt = 0; nt < 4; ++nt) {
        const float* p = xb + (nt*16 + l15)*32 + q4*8;
        float4 u0 = *(const float4*)p;
        float4 u1 = *(const float4*)(p + 4);
        S8U t;
        t.u[0] = pk2(u0.x, u0.y); t.u[1] = pk2(u0.z, u0.w);
        t.u[2] = pk2(u1.x, u1.y); t.u[3] = pk2(u1.z, u1.w);
        xa[nt] = t.s;
    }

    auto wrow = [&](const float* W, int row) -> short8 {
        const float* p = W + row*32 + q4*8;
        float4 u0 = *(const float4*)p;
        float4 u1 = *(const float4*)(p + 4);
        S8U t;
        t.u[0] = pk2(u0.x, u0.y); t.u[1] = pk2(u0.z, u0.w);
        t.u[2] = pk2(u1.x, u1.y); t.u[3] = pk2(u1.z, u1.w);
        return t.s;
    };

    const float escale = 0.35355339059327373f * 1.4426950408889634f; // 1/sqrt(8)*log2(e)

    // ---- Q^T (this wave's 16 dims) -> registers, bias+scale in f32 ----
    unsigned qpk01[4], qpk23[4];
    {
        short8 wa = wrow(Wq, 16*w + l15);
        float4 b4 = *(const float4*)(bq + 16*w + q4*4);
#pragma unroll
        for (int nt = 0; nt < 4; ++nt) {
            f32x4 acc = {0.f,0.f,0.f,0.f};
            acc = MFMA(wa, xa[nt], acc, 0,0,0);
            qpk01[nt] = pk2((acc[0]+b4.x)*escale, (acc[1]+b4.y)*escale);
            qpk23[nt] = pk2((acc[2]+b4.z)*escale, (acc[3]+b4.w)*escale);
        }
    }
    // ---- K^T (this wave's 16 dims) -> klds cols 16w.. ----
    {
        short8 wa = wrow(Wk, 16*w + l15);
        float4 b4 = *(const float4*)(bk + 16*w + q4*4);
#pragma unroll
        for (int nt = 0; nt < 4; ++nt) {
            f32x4 acc = {0.f,0.f,0.f,0.f};
            acc = MFMA(wa, xa[nt], acc, 0,0,0);
            uint2 w2;
            w2.x = pk2(acc[0]+b4.x, acc[1]+b4.y);
            w2.y = pk2(acc[2]+b4.z, acc[3]+b4.w);
            *(uint2*)&klds[nt*16 + l15][16*w + q4*4] = w2;
        }
    }
    // ---- V (this wave's 16 dims) -> vbt rows 16w.. (V transposed) ----
    {
        short8 wv = wrow(Wv, 16*w + l15);
        const float bvv = bv[16*w + l15];
#pragma unroll
        for (int mt = 0; mt < 4; ++mt) {
            f32x4 acc = {0.f,0.f,0.f,0.f};
            acc = MFMA(xa[mt], wv, acc, 0,0,0);
            uint2 w2;
            w2.x = pk2(acc[0]+bvv, acc[1]+bvv);
            w2.y = pk2(acc[2]+bvv, acc[3]+bvv);
            *(uint2*)&vbt[16*w + l15][mt*16 + q4*4] = w2;
        }
    }
    // ones row 32 (each wave writes identical bits -> benign duplicate)
    if (q4 == 0) {
        uint2 ones; ones.x = 0x3F803F80u; ones.y = 0x3F803F80u;
        *(uint2*)&vbt[32][l15*4] = ones;
    }
    LDSFENCE();   // wave reads only its own staging regions -> no barrier

    // ---- head loop (2 heads per wave): produce packed O-frags only ----
    unsigned opk01s[2][4], opk23s[2][4];

#pragma unroll
    for (int hl = 0; hl < 2; ++hl) {
        const int idxA = (32*hl + l15) * 4;        // lane (q4=2hl,   l15)
        const int idxB = idxA + 64;                // lane (q4=2hl+1, l15)

        // Q B-frags: zero k>=8 via bmask
        short8 sqb[4];
#pragma unroll
        for (int it = 0; it < 4; ++it) {
            S8U t;
            t.u[0] = (unsigned)BPERM(idxA, (int)qpk01[it]) & bmask;
            t.u[1] = (unsigned)BPERM(idxA, (int)qpk23[it]) & bmask;
            t.u[2] = (unsigned)BPERM(idxB, (int)qpk01[it]) & bmask;
            t.u[3] = (unsigned)BPERM(idxB, (int)qpk23[it]) & bmask;
            sqb[it] = t.s;
        }

        // V^T A-frag row: dims for l15<8, ones row (colsum) for l15>=8
        const int avrow = (l15 < 8) ? (16*w + 8*hl + l15) : 32;
        const short* avbase = &vbt[avrow][0];

        f32x4 oacch[4];
#pragma unroll
        for (int it = 0; it < 4; ++it) oacch[it] = (f32x4){0.f,0.f,0.f,0.f};

#pragma unroll
        for (int jb = 0; jb < 2; ++jb) {
            // K A-frags: q4-uniform broadcast rows (16B-aligned, 80B stride)
            short8 ska[2];
#pragma unroll
            for (int jt = 0; jt < 2; ++jt) {
                S8U t; t.v = *(const uint4*)&klds[jb*32 + jt*16 + l15][16*w + 8*hl];
                ska[jt] = t.s;
            }
            S8U av; av.v = *(const uint4*)&avbase[jb*32 + q4*8];

#pragma unroll
            for (int it = 0; it < 4; ++it) {
#pragma unroll
                for (int jt = 0; jt < 2; ++jt) {
                    f32x4 sacc = {0.f,0.f,0.f,0.f};
                    sacc = MFMA(ska[jt], sqb[it], sacc, 0,0,0);
                    float e[4];
#pragma unroll
                    for (int r = 0; r < 4; ++r) {
                        float ee = __builtin_amdgcn_exp2f(sacc[r]);
                        e[r] = (jb*32 + jt*16 + r <= cmpv[it]) ? ee : 0.0f;
                    }
                    uint2 pw; pw.x = pk2(e[0], e[1]); pw.y = pk2(e[2], e[3]);
                    *(uint2*)&psl[w][l15][jt*16 + q4*4] = pw;
                }
                LDSFENCE();
                S8U pb; pb.v = *(const uint4*)&psl[w][l15][q4*8];
                oacch[it] = MFMA(av.s, pb.s, oacch[it], 0,0,0);
                LDSFENCE();
            }
        }

        // colsum arrived in C-row 8 (lane 32+l15, reg 0) via the ones row
#pragma unroll
        for (int it = 0; it < 4; ++it) {
            FI s; s.i = BPERM((32 + l15) * 4, __builtin_bit_cast(int, oacch[it][0]));
            const float inv = __builtin_amdgcn_rcpf(s.f);
            opk01s[hl][it] = pk2(oacch[it][0]*inv, oacch[it][1]*inv);
            opk23s[hl][it] = pk2(oacch[it][2]*inv, oacch[it][3]*inv);
        }
    }

    // ---- tail: concat-head out-projection via reclaimed klds ----
    __syncthreads();   // all klds (K) reads complete in both waves
    // O[i][dim0..31] (4 heads x 8), packed bf16; only q4<2 lanes hold data
    if (q4 < 2) {
#pragma unroll
        for (int hl = 0; hl < 2; ++hl)
#pragma unroll
            for (int it = 0; it < 4; ++it) {
                uint2 ow; ow.x = opk01s[hl][it]; ow.y = opk23s[hl][it];
                *(uint2*)&klds[it*16 + l15][(2*w + hl)*8 + q4*4] = ow;
            }
    }
    __syncthreads();

    // full-K Wp B-frags (no masking: k = q4*8+e spans all 32 inner dims)
    short8 wpb[2];
#pragma unroll
    for (int nt = 0; nt < 2; ++nt) wpb[nt] = wrow(Wp, nt*16 + l15);

    const float bpv[2] = { bp[l15], bp[16 + l15] };
    float* ob = out + (size_t)b * 64 * 32;
#pragma unroll
    for (int u = 0; u < 2; ++u) {           // this wave's i-tiles: 2w, 2w+1
        S8U oa; oa.v = *(const uint4*)&klds[(2*w + u)*16 + l15][q4*8];
#pragma unroll
        for (int nt = 0; nt < 2; ++nt) {
            f32x4 y = {0.f,0.f,0.f,0.f};
            y = MFMA(oa.s, wpb[nt], y, 0,0,0);
#pragma unroll
            for (int r = 0; r < 4; ++r)
                ob[((2*w + u)*16 + q4*4 + r)*32 + nt*16 + l15] = y[r] + bpv[nt];
        }
    }
}

extern "C" void kernel_launch(void* const* d_in, const int* in_sizes, int n_in,
                              void* d_out, int out_size, void* d_ws, size_t ws_size,
                              hipStream_t stream) {
    const float* x  = (const float*)d_in[0];
    const int*   aa = (const int*)d_in[1];
    const float* Wq = (const float*)d_in[2];
    const float* bq = (const float*)d_in[3];
    const float* Wk = (const float*)d_in[4];
    const float* bk = (const float*)d_in[5];
    const float* Wv = (const float*)d_in[6];
    const float* bv = (const float*)d_in[7];
    const float* Wp = (const float*)d_in[8];
    const float* bp = (const float*)d_in[9];
    float* out = (float*)d_out;

    dim3 grid(NB), block(128);
    hipLaunchKernelGGL(fused_attn_mfma, grid, block, 0, stream,
                       x, aa, Wq, bq, Wk, bk, Wv, bv, Wp, bp, out);
}